// Round 4
// baseline (790.176 us; speedup 1.0000x reference)
//
#include <hip/hip_runtime.h>
#include <math.h>

// SigmoidRouter: x(16384,4096) f32, gate_w(64,4096) f32, bias(64) f32
// out (float*): weights[tokens*8] ++ indices-as-float[tokens*8] ++ loss[1]
//
// Correctness strategy: logits in f64 (f32 accumulation gives ~1e-6 error ->
// top-k near-tie index flips vs the np reference). Top-k comparisons on f64
// logits; emitted weight/loss values in f32 (2% threshold).

constexpr int DIM     = 4096;
constexpr int NE      = 64;
constexpr int TOPK    = 8;
constexpr float EPS   = 1e-6f;
constexpr int TPB_TOK = 16;      // tokens per block (4 waves x 4 tokens)
constexpr int KC      = 256;     // K chunk staged in LDS (as f64)

__device__ inline double shfl_xor_d(double v, int off) {
    long long x = __double_as_longlong(v);
    int lo = (int)(unsigned int)(x & 0xffffffffLL);
    int hi = (int)(x >> 32);
    lo = __shfl_xor(lo, off);
    hi = __shfl_xor(hi, off);
    long long y = ((long long)hi << 32) | (unsigned int)lo;
    return __longlong_as_double(y);
}

// gw [64][4096] f32  ->  gwd2 [2048][64] double2, element (k2,e) = {gw[e][2k2], gw[e][2k2+1]}
__global__ __launch_bounds__(256)
void transpose_gw(const float* __restrict__ gw, double2* __restrict__ gwd2)
{
    int idx = blockIdx.x * 256 + threadIdx.x;      // [0, 2048*64)
    int e  = idx & 63;
    int k2 = idx >> 6;
    float g0 = gw[(size_t)e * DIM + 2 * k2];
    float g1 = gw[(size_t)e * DIM + 2 * k2 + 1];
    double2 d; d.x = (double)g0; d.y = (double)g1;
    gwd2[idx] = d;
}

__global__ __launch_bounds__(256, 4)
void router_main(const float* __restrict__ x, const double2* __restrict__ gwd2,
                 const float* __restrict__ bias, float* __restrict__ out,
                 float* __restrict__ ws_ssum, float* __restrict__ ws_cnt,
                 int tokens)
{
    __shared__ double xt[TPB_TOK][KC];       // 32 KB
    __shared__ float red_s[4][NE];
    __shared__ float red_c[4][NE];

    const int tid  = threadIdx.x;
    const int wave = tid >> 6;
    const int lane = tid & 63;
    const int tok0 = blockIdx.x * TPB_TOK;
    const int wtok = tok0 + wave * 4;
    const int w4   = wave * 4;

    double accA0 = 0, accA1 = 0, accA2 = 0, accA3 = 0;
    double accB0 = 0, accB1 = 0, accB2 = 0, accB3 = 0;

    const double2* gbase = gwd2 + lane;      // (k2, e=lane) at gbase[k2*64]

    for (int kc = 0; kc < DIM; kc += KC) {
        __syncthreads();
        // stage x[tok0..tok0+15][kc..kc+KC) -> LDS as f64; wave w stages row i*4+w
        #pragma unroll
        for (int i = 0; i < 4; ++i) {
            int r  = i * 4 + wave;
            int c4 = lane;                   // float4 column
            float4 v = *reinterpret_cast<const float4*>(
                &x[(size_t)(tok0 + r) * DIM + kc + c4 * 4]);
            double2 d0; d0.x = (double)v.x; d0.y = (double)v.y;
            double2 d1; d1.x = (double)v.z; d1.y = (double)v.w;
            *reinterpret_cast<double2*>(&xt[r][c4 * 4 + 0]) = d0;
            *reinterpret_cast<double2*>(&xt[r][c4 * 4 + 2]) = d1;
        }
        __syncthreads();

        const int k2base = kc >> 1;
        #pragma unroll 4
        for (int k2 = 0; k2 < KC / 2; k2 += 2) {
            double2 g0 = gbase[(size_t)(k2base + k2) * 64];
            double2 g1 = gbase[(size_t)(k2base + k2 + 1) * 64];
            double2 a0 = *reinterpret_cast<const double2*>(&xt[w4 + 0][2 * k2]);
            double2 b0 = *reinterpret_cast<const double2*>(&xt[w4 + 0][2 * k2 + 2]);
            accA0 = fma(g0.x, a0.x, accA0); accA0 = fma(g0.y, a0.y, accA0);
            accB0 = fma(g1.x, b0.x, accB0); accB0 = fma(g1.y, b0.y, accB0);
            double2 a1 = *reinterpret_cast<const double2*>(&xt[w4 + 1][2 * k2]);
            double2 b1 = *reinterpret_cast<const double2*>(&xt[w4 + 1][2 * k2 + 2]);
            accA1 = fma(g0.x, a1.x, accA1); accA1 = fma(g0.y, a1.y, accA1);
            accB1 = fma(g1.x, b1.x, accB1); accB1 = fma(g1.y, b1.y, accB1);
            double2 a2 = *reinterpret_cast<const double2*>(&xt[w4 + 2][2 * k2]);
            double2 b2 = *reinterpret_cast<const double2*>(&xt[w4 + 2][2 * k2 + 2]);
            accA2 = fma(g0.x, a2.x, accA2); accA2 = fma(g0.y, a2.y, accA2);
            accB2 = fma(g1.x, b2.x, accB2); accB2 = fma(g1.y, b2.y, accB2);
            double2 a3 = *reinterpret_cast<const double2*>(&xt[w4 + 3][2 * k2]);
            double2 b3 = *reinterpret_cast<const double2*>(&xt[w4 + 3][2 * k2 + 2]);
            accA3 = fma(g0.x, a3.x, accA3); accA3 = fma(g0.y, a3.y, accA3);
            accB3 = fma(g1.x, b3.x, accB3); accB3 = fma(g1.y, b3.y, accB3);
        }
    }

    const double b = (double)bias[lane];
    double dl[4] = {accA0 + accB0 + b, accA1 + accB1 + b,
                    accA2 + accB2 + b, accA3 + accB3 + b};

    float my_ssum = 0.f;
    float my_cnt  = 0.f;

    #pragma unroll
    for (int j = 0; j < 4; ++j) {
        float sig = 1.f / (1.f + expf(-(float)dl[j]));
        float S = sig;
        #pragma unroll
        for (int off = 32; off; off >>= 1) S += __shfl_xor(S, off);
        float ns = sig / (S + EPS);
        my_ssum += ns;

        double key = dl[j];                  // compare in f64: order == score order
        float topsum = 0.f;
        float myval  = 0.f;
        int   myidx  = 0;
        #pragma unroll
        for (int k = 0; k < TOPK; ++k) {
            double kv = key; int id = lane;
            #pragma unroll
            for (int off = 32; off; off >>= 1) {
                double okv = shfl_xor_d(kv, off);
                int    oi  = __shfl_xor(id, off);
                if (okv > kv || (okv == kv && oi < id)) { kv = okv; id = oi; }
            }
            float nsw = __shfl(ns, id);      // winner's normalized score
            topsum += nsw;
            if (lane == k)  { myval = nsw; myidx = id; }
            if (lane == id) { key = -1.0e300; my_cnt += 1.f; }
        }
        float wnorm = myval / (topsum + EPS);
        int tok = wtok + j;
        if (lane < TOPK) {
            out[(size_t)tok * TOPK + lane] = wnorm;
            out[(size_t)tokens * TOPK + (size_t)tok * TOPK + lane] = (float)myidx;
        }
    }

    red_s[wave][lane] = my_ssum;
    red_c[wave][lane] = my_cnt;
    __syncthreads();
    if (tid < NE) {
        float s = red_s[0][tid] + red_s[1][tid] + red_s[2][tid] + red_s[3][tid];
        float c = red_c[0][tid] + red_c[1][tid] + red_c[2][tid] + red_c[3][tid];
        ws_ssum[(size_t)blockIdx.x * NE + tid] = s;
        ws_cnt [(size_t)blockIdx.x * NE + tid] = c;
    }
}

__global__ __launch_bounds__(256)
void router_loss(const float* __restrict__ ws_ssum, const float* __restrict__ ws_cnt,
                 float* __restrict__ out, int nblocks, int tokens)
{
    __shared__ float ps[4][NE];
    __shared__ float pc[4][NE];
    const int e  = threadIdx.x & 63;
    const int sl = threadIdx.x >> 6;
    float s = 0.f, c = 0.f;
    for (int bb = sl; bb < nblocks; bb += 4) {
        s += ws_ssum[(size_t)bb * NE + e];
        c += ws_cnt [(size_t)bb * NE + e];
    }
    ps[sl][e] = s; pc[sl][e] = c;
    __syncthreads();
    if (threadIdx.x < NE) {
        float st = ps[0][e] + ps[1][e] + ps[2][e] + ps[3][e];
        float ct = pc[0][e] + pc[1][e] + pc[2][e] + pc[3][e];
        float prod = st * ct;
        #pragma unroll
        for (int off = 32; off; off >>= 1) prod += __shfl_xor(prod, off);
        if (threadIdx.x == 0) {
            float T = (float)tokens;
            out[(size_t)tokens * TOPK * 2] = (float)NE * prod / (T * T);
        }
    }
}

extern "C" void kernel_launch(void* const* d_in, const int* in_sizes, int n_in,
                              void* d_out, int out_size, void* d_ws, size_t ws_size,
                              hipStream_t stream)
{
    const float* x    = (const float*)d_in[0];
    const float* gw   = (const float*)d_in[1];
    const float* bias = (const float*)d_in[2];
    float* out = (float*)d_out;

    const int tokens  = in_sizes[0] / DIM;        // 16384
    const int nblocks = tokens / TPB_TOK;         // 1024

    double2* gwd2  = (double2*)d_ws;                               // 2 MB
    float* ws_ssum = (float*)((char*)d_ws + (size_t)(DIM / 2) * NE * sizeof(double2));
    float* ws_cnt  = ws_ssum + (size_t)nblocks * NE;

    transpose_gw<<<(DIM / 2) * NE / 256, 256, 0, stream>>>(gw, gwd2);
    router_main<<<nblocks, 256, 0, stream>>>(x, gwd2, bias, out, ws_ssum, ws_cnt, tokens);
    router_loss<<<1, 256, 0, stream>>>(ws_ssum, ws_cnt, out, nblocks, tokens);
}